// Round 4
// baseline (224.461 us; speedup 1.0000x reference)
//
#include <hip/hip_runtime.h>
#include <hip/hip_bf16.h>

typedef __bf16 bf16x8 __attribute__((ext_vector_type(8)));
typedef float f32x4 __attribute__((ext_vector_type(4)));
typedef float f32x16 __attribute__((ext_vector_type(16)));
typedef unsigned short ushort_t;
typedef unsigned int uint2v __attribute__((ext_vector_type(2)));

#define DEVI __device__ __forceinline__

static constexpr int KDIM = 1024;   // d_model
static constexpr int SEQ  = 2048;
static constexpr size_t TEN = 4194304; // 4096*1024 elements per tensor

DEVI ushort_t f2bf(float f) {
  union { float f; unsigned u; } a; a.f = f;
  unsigned u = a.u;
  return (ushort_t)((u + 0x7FFFu + ((u >> 16) & 1u)) >> 16);
}

DEVI unsigned cvtpk(float lo, float hi) {   // word = {bf16(hi)<<16 | bf16(lo)}
  unsigned r;
  asm("v_cvt_pk_bf16_f32 %0, %1, %2" : "=v"(r) : "v"(lo), "v"(hi));
  return r;
}

// validated permlane path (m240/m214): builtin, compiler handles hazards.
DEVI uint2v plswap(unsigned a, unsigned b) {
  return __builtin_amdgcn_permlane32_swap(a, b, 0, 0);
}
DEVI float swap_max(float x) {
  union { float f; unsigned u; } a; a.f = x;
  const uint2v r = plswap(a.u, a.u);
  union { unsigned u; float f; } p0, p1; p0.u = r[0]; p1.u = r[1];
  return fmaxf(p0.f, p1.f);
}
DEVI float swap_sum(float x) {
  union { float f; unsigned u; } a; a.f = x;
  const uint2v r = plswap(a.u, a.u);
  union { unsigned u; float f; } p0, p1; p0.u = r[0]; p1.u = r[1];
  return p0.f + p1.f;
}

DEVI void gload16(const ushort_t* g, ushort_t* l) {
  __builtin_amdgcn_global_load_lds(
      (const __attribute__((address_space(1))) void*)g,
      (__attribute__((address_space(3))) void*)l,
      16, 0, 0);
}

// ---------------- fused casts: x (1M float4) then Wq|Wk|Wv|Wo (1M float4) ----------------
__global__ void cast_all(const float* __restrict__ x,
                         const float* __restrict__ w0, const float* __restrict__ w1,
                         const float* __restrict__ w2, const float* __restrict__ w3,
                         ushort_t* __restrict__ xb, ushort_t* __restrict__ wb) {
  const int i = blockIdx.x * 256 + threadIdx.x;   // [0, 2M)
  float4 v; ushort_t* dst; int idx;
  if (i < (1 << 20)) {
    v = ((const float4*)x)[i]; dst = xb; idx = i;
  } else {
    const int j = i - (1 << 20);
    const int which = j >> 18;
    const float* w = which == 0 ? w0 : which == 1 ? w1 : which == 2 ? w2 : w3;
    v = ((const float4*)w)[j & 262143]; dst = wb; idx = j;
  }
  ushort4 o;
  o.x = f2bf(v.x); o.y = f2bf(v.y); o.z = f2bf(v.z); o.w = f2bf(v.w);
  ((ushort4*)dst)[idx] = o;
}

// ---------------- GEMM: C = A(M,K) * B(N,K)^T, bf16 in, 128x128 tile ----------------
// MODE 0: QKV fused (N=3072): Q,K -> (b,h,s,d) bf16; V -> V^T (b,h,d,s) bf16
// MODE 1: fp32 row-major store (output projection)
template<int MODE>
__global__ __launch_bounds__(256, 3) void gemm128(const ushort_t* __restrict__ A,
                                                  const ushort_t* __restrict__ Bm,
                                                  ushort_t* __restrict__ obf,
                                                  ushort_t* __restrict__ vt,
                                                  float* __restrict__ ofp) {
  __shared__ ushort_t smA[128 * 64];
  __shared__ ushort_t smB[128 * 64];
  const int tid = threadIdx.x;
  const int w = tid >> 6, l = tid & 63;
  const int lg = l >> 4, ll = l & 15;
  const int lr = l >> 3, lc = (l & 7) * 8;
  const int m0 = blockIdx.y * 128, n0 = blockIdx.x * 128;
  const int wm = (w >> 1) * 64, wn = (w & 1) * 64;

  f32x4 acc[4][4];
#pragma unroll
  for (int i = 0; i < 4; ++i)
#pragma unroll
    for (int j = 0; j < 4; ++j) acc[i][j] = f32x4{0.f, 0.f, 0.f, 0.f};

  for (int k0 = 0; k0 < KDIM; k0 += 64) {
    __syncthreads();
#pragma unroll
    for (int i = 0; i < 4; ++i) {
      const int ci = w * 4 + i;
      gload16(A  + (size_t)(m0 + ci * 8 + lr) * KDIM + k0 + lc, smA + ci * 512);
      gload16(Bm + (size_t)(n0 + ci * 8 + lr) * KDIM + k0 + lc, smB + ci * 512);
    }
    __syncthreads();
#pragma unroll
    for (int ks = 0; ks < 2; ++ks) {
      bf16x8 af[4], bfr[4];
#pragma unroll
      for (int t = 0; t < 4; ++t) {
        af[t]  = *(const bf16x8*)(smA + (wm + t * 16 + ll) * 64 + ks * 32 + lg * 8);
        bfr[t] = *(const bf16x8*)(smB + (wn + t * 16 + ll) * 64 + ks * 32 + lg * 8);
      }
      __builtin_amdgcn_s_setprio(1);
#pragma unroll
      for (int i = 0; i < 4; ++i)
#pragma unroll
        for (int j = 0; j < 4; ++j)
          acc[i][j] = __builtin_amdgcn_mfma_f32_16x16x32_bf16(af[i], bfr[j], acc[i][j], 0, 0, 0);
      __builtin_amdgcn_s_setprio(0);
    }
  }

#pragma unroll
  for (int i = 0; i < 4; ++i) {
#pragma unroll
    for (int j = 0; j < 4; ++j) {
      const int gm0 = m0 + wm + i * 16 + 4 * lg;
      const int gn = n0 + wn + j * 16 + ll;
      if (MODE == 0) {
        const int which = gn >> 10, nn = gn & 1023;
        const int h = nn >> 6, d = nn & 63;
        const int b = gm0 >> 11, s0 = gm0 & 2047;
        if (which == 2) {   // V: store transposed (b,h,d,s), 4 consecutive s packed
          const unsigned u0 = cvtpk(acc[i][j][0], acc[i][j][1]);
          const unsigned u1 = cvtpk(acc[i][j][2], acc[i][j][3]);
          *(uint2v*)(vt + ((size_t)(b * 16 + h) * 64 + d) * 2048 + s0) = uint2v{u0, u1};
        } else {
#pragma unroll
          for (int r = 0; r < 4; ++r)
            obf[(size_t)which * TEN + (((size_t)(b * 16 + h) * 2048 + s0 + r) * 64 + d)] =
                f2bf(acc[i][j][r]);
        }
      } else {
#pragma unroll
        for (int r = 0; r < 4; ++r)
          ofp[(size_t)(gm0 + r) * 1024 + gn] = acc[i][j][r];
      }
    }
  }
}

// ---------------- causal flash attention v3: LDS-free, swapped 32x32 QK^T ----------------
// grid (16, 32): x = q-tile (128 rows), y = bh. 4 waves x 32 q-rows. KV tile 64.
// Per lane: one q-row. S^T via mfma(Kfrag, Qfrag): lane l&31 = q-col, regs = kv-rows.
__global__ __launch_bounds__(256, 3) void attn_fwd(const ushort_t* __restrict__ Qg,
                                                   const ushort_t* __restrict__ Kg,
                                                   const ushort_t* __restrict__ Vtg,
                                                   ushort_t* __restrict__ ao) {
  const int tid = threadIdx.x;
  const int w = tid >> 6, l = tid & 63;
  const int l31 = l & 31, hi = l >> 5;
  const int bh = blockIdx.y;
  // complementary pairing: batch 0 vs batch 1 get qx and 15-qx
  const int qx = ((bh >> 4) & 1) ? (15 - (int)blockIdx.x) : (int)blockIdx.x;
  const int q0 = qx * 128;
  const int q = q0 + w * 32 + l31;           // this lane's q-row
  const ushort_t* Qb = Qg  + (size_t)bh * (SEQ * 64);
  const ushort_t* Kb = Kg  + (size_t)bh * (SEQ * 64);
  const ushort_t* Vb = Vtg + (size_t)bh * (SEQ * 64);

  // Q fragments (B-operand): lane supplies Q[q][16ks + 8hi .. +7]
  bf16x8 qf[4];
#pragma unroll
  for (int ks = 0; ks < 4; ++ks)
    qf[ks] = *(const bf16x8*)(Qb + (size_t)q * 64 + ks * 16 + hi * 8);

  f32x16 oT[2];
#pragma unroll
  for (int dh = 0; dh < 2; ++dh)
#pragma unroll
    for (int r = 0; r < 16; ++r) oT[dh][r] = 0.f;
  float mi = -3.0e38f, li = 0.f;

  const float SCL2 = 0.18033688011112042f;   // (1/8) * log2(e)
  const int myNkt = (q0 + 32 * w + 31) / 64 + 1;   // causal per-wave trip count

  for (int kt = 0; kt < myNkt; ++kt) {
    const int kv0 = kt * 64;

    // ---- QK^T: S^T[kv][q], two kv-halves ----
    f32x16 sc[2];
#pragma unroll
    for (int h2 = 0; h2 < 2; ++h2)
#pragma unroll
      for (int r = 0; r < 16; ++r) sc[h2][r] = 0.f;
    __builtin_amdgcn_s_setprio(1);
#pragma unroll
    for (int h2 = 0; h2 < 2; ++h2)
#pragma unroll
      for (int ks = 0; ks < 4; ++ks) {
        const bf16x8 kf = *(const bf16x8*)(Kb + (size_t)(kv0 + h2 * 32 + l31) * 64 + ks * 16 + hi * 8);
        sc[h2] = __builtin_amdgcn_mfma_f32_32x32x16_bf16(kf, qf[ks], sc[h2], 0, 0, 0);
      }
    __builtin_amdgcn_s_setprio(0);

    // ---- causal mask (last tile of this wave only) ----
    // sc[h2][r] = S[q][kv0 + 32*h2 + crow(r,hi)], crow = (r&3)+8*(r>>2)+4*hi
    if (kt == myNkt - 1) {
      const int thr0 = q - kv0 - 4 * hi;
#pragma unroll
      for (int r = 0; r < 16; ++r) {
        const int cr = (r & 3) + 8 * (r >> 2);
        if (cr > thr0)      sc[0][r] = -3.0e38f;
        if (cr > thr0 - 32) sc[1][r] = -3.0e38f;
      }
    }

    // ---- in-lane row max (raw domain) + cross-half swap ----
    float t8[8];
#pragma unroll
    for (int r = 0; r < 8; ++r)
      t8[r] = fmaxf(fmaxf(sc[0][r], sc[0][r + 8]), fmaxf(sc[1][r], sc[1][r + 8]));
    float mx = fmaxf(fmaxf(fmaxf(t8[0], t8[1]), fmaxf(t8[2], t8[3])),
                     fmaxf(fmaxf(t8[4], t8[5]), fmaxf(t8[6], t8[7])));
    mx = swap_max(mx);

    // ---- defer-max rescale (T13, THR = 8 in exp2 domain = 44.36 raw) ----
    if (!__all(mx <= mi + 44.0f)) {
      const float mnew = fmaxf(mi, mx);
      const float al = __builtin_amdgcn_exp2f((mi - mnew) * SCL2);
      li *= al;
#pragma unroll
      for (int dh = 0; dh < 2; ++dh)
#pragma unroll
        for (int r = 0; r < 16; ++r) oT[dh][r] *= al;
      mi = mnew;
    }

    // ---- P = exp2(S*scale - mi*scale), in-lane sum tree ----
    const float ms = mi * SCL2;
#pragma unroll
    for (int h2 = 0; h2 < 2; ++h2)
#pragma unroll
      for (int r = 0; r < 16; ++r)
        sc[h2][r] = __builtin_amdgcn_exp2f(__builtin_fmaf(sc[h2][r], SCL2, -ms));
    float s8[8];
#pragma unroll
    for (int r = 0; r < 8; ++r)
      s8[r] = (sc[0][r] + sc[0][r + 8]) + (sc[1][r] + sc[1][r + 8]);
    float sum = ((s8[0] + s8[1]) + (s8[2] + s8[3])) + ((s8[4] + s8[5]) + (s8[6] + s8[7]));
    li += swap_sum(sum);

    // ---- pack P -> bf16 B-fragments (T12: cvt_pk + permlane32_swap builtin) ----
    bf16x8 pf[4];
#pragma unroll
    for (int m = 0; m < 4; ++m) {
      const int H = m >> 1, base = (m & 1) * 8;
      const unsigned a0 = cvtpk(sc[H][base + 0], sc[H][base + 1]);
      const unsigned a1 = cvtpk(sc[H][base + 2], sc[H][base + 3]);
      const unsigned a2 = cvtpk(sc[H][base + 4], sc[H][base + 5]);
      const unsigned a3 = cvtpk(sc[H][base + 6], sc[H][base + 7]);
      const uint2v r02 = plswap(a0, a2);   // {new a0, new a2}
      const uint2v r13 = plswap(a1, a3);
      union { unsigned u[4]; bf16x8 v; } cv;
      cv.u[0] = r02[0]; cv.u[1] = r13[0]; cv.u[2] = r02[1]; cv.u[3] = r13[1];
      pf[m] = cv.v;
    }

    // ---- PV: O^T[d][q] += V^T[d][kv] * P^T[kv][q] ----
    __builtin_amdgcn_s_setprio(1);
#pragma unroll
    for (int dh = 0; dh < 2; ++dh)
#pragma unroll
      for (int m = 0; m < 4; ++m) {
        const bf16x8 vf = *(const bf16x8*)(Vb + (size_t)(dh * 32 + l31) * SEQ + kv0 + m * 16 + hi * 8);
        oT[dh] = __builtin_amdgcn_mfma_f32_32x32x16_bf16(vf, pf[m], oT[dh], 0, 0, 0);
      }
    __builtin_amdgcn_s_setprio(0);
  }

  // ---- epilogue: O = O^T / li, packed 8B stores to (b, s, h*64+d) ----
  const float inv = 1.f / li;
  const int b = bh >> 4, h = bh & 15;
  ushort_t* orow = ao + ((size_t)b * 2048 + q) * 1024 + h * 64;
#pragma unroll
  for (int dh = 0; dh < 2; ++dh)
#pragma unroll
    for (int rg = 0; rg < 4; ++rg) {
      const unsigned u0 = cvtpk(oT[dh][4 * rg + 0] * inv, oT[dh][4 * rg + 1] * inv);
      const unsigned u1 = cvtpk(oT[dh][4 * rg + 2] * inv, oT[dh][4 * rg + 3] * inv);
      *(uint2v*)(orow + dh * 32 + hi * 4 + rg * 8) = uint2v{u0, u1};
    }
}

// ---------------- launch ----------------
extern "C" void kernel_launch(void* const* d_in, const int* in_sizes, int n_in,
                              void* d_out, int out_size, void* d_ws, size_t ws_size,
                              hipStream_t stream) {
  (void)in_sizes; (void)n_in; (void)out_size; (void)ws_size;
  const float* x  = (const float*)d_in[0];
  const float* wq = (const float*)d_in[1];
  const float* wk = (const float*)d_in[2];
  const float* wv = (const float*)d_in[3];
  const float* wo = (const float*)d_in[4];

  char* ws = (char*)d_ws;
  ushort_t* xb  = (ushort_t*)ws;                     // 8 MiB; reused as attn-out later
  ushort_t* wb  = (ushort_t*)(ws + (8u  << 20));     // 8 MiB: Wq,Wk,Wv,Wo bf16 contiguous
  ushort_t* qkv = (ushort_t*)(ws + (16u << 20));     // Q,K in (b,h,s,d)
  ushort_t* vt  = (ushort_t*)(ws + (40u << 20));     // 8 MiB: V^T in (b,h,d,s)
  ushort_t* ao  = xb;                                // attention output (b,s,h*64+d)
  float* out = (float*)d_out;

  cast_all<<<8192, 256, 0, stream>>>(x, wq, wk, wv, wo, xb, wb);
  gemm128<0><<<dim3(24, 32), 256, 0, stream>>>(xb, wb, qkv, vt, nullptr);
  attn_fwd  <<<dim3(16, 32), 256, 0, stream>>>(qkv, qkv + TEN, vt, ao);
  gemm128<1><<<dim3(8, 32), 256, 0, stream>>>(ao, wb + 3 * 1048576, nullptr, nullptr, out);
}

// Round 5
// 176.630 us; speedup vs baseline: 1.2708x; 1.2708x over previous
//
#include <hip/hip_runtime.h>
#include <hip/hip_bf16.h>

typedef __bf16 bf16x8 __attribute__((ext_vector_type(8)));
typedef float f32x4 __attribute__((ext_vector_type(4)));
typedef float f32x16 __attribute__((ext_vector_type(16)));
typedef unsigned short ushort_t;
typedef unsigned int uint2v __attribute__((ext_vector_type(2)));

#define DEVI __device__ __forceinline__

static constexpr int KDIM = 1024;   // d_model
static constexpr int SEQ  = 2048;
static constexpr size_t TEN = 4194304; // 4096*1024 elements per tensor

DEVI ushort_t f2bf(float f) {
  union { float f; unsigned u; } a; a.f = f;
  unsigned u = a.u;
  return (ushort_t)((u + 0x7FFFu + ((u >> 16) & 1u)) >> 16);
}

DEVI unsigned cvtpk(float lo, float hi) {   // word = {bf16(hi)<<16 | bf16(lo)}
  unsigned r;
  asm("v_cvt_pk_bf16_f32 %0, %1, %2" : "=v"(r) : "v"(lo), "v"(hi));
  return r;
}

// validated permlane path (m240/m214): builtin, compiler handles hazards.
DEVI uint2v plswap(unsigned a, unsigned b) {
  return __builtin_amdgcn_permlane32_swap(a, b, 0, 0);
}
DEVI float swap_max(float x) {
  union { float f; unsigned u; } a; a.f = x;
  const uint2v r = plswap(a.u, a.u);
  union { unsigned u; float f; } p0, p1; p0.u = r[0]; p1.u = r[1];
  return fmaxf(p0.f, p1.f);
}
DEVI float swap_sum(float x) {
  union { float f; unsigned u; } a; a.f = x;
  const uint2v r = plswap(a.u, a.u);
  union { unsigned u; float f; } p0, p1; p0.u = r[0]; p1.u = r[1];
  return p0.f + p1.f;
}

DEVI void gload16(const ushort_t* g, ushort_t* l) {
  __builtin_amdgcn_global_load_lds(
      (const __attribute__((address_space(1))) void*)g,
      (__attribute__((address_space(3))) void*)l,
      16, 0, 0);
}

// ---------------- fused casts: x (1M float4) then Wq|Wk|Wv|Wo (1M float4) ----------------
__global__ void cast_all(const float* __restrict__ x,
                         const float* __restrict__ w0, const float* __restrict__ w1,
                         const float* __restrict__ w2, const float* __restrict__ w3,
                         ushort_t* __restrict__ xb, ushort_t* __restrict__ wb) {
  const int i = blockIdx.x * 256 + threadIdx.x;   // [0, 2M)
  float4 v; ushort_t* dst; int idx;
  if (i < (1 << 20)) {
    v = ((const float4*)x)[i]; dst = xb; idx = i;
  } else {
    const int j = i - (1 << 20);
    const int which = j >> 18;
    const float* w = which == 0 ? w0 : which == 1 ? w1 : which == 2 ? w2 : w3;
    v = ((const float4*)w)[j & 262143]; dst = wb; idx = j;
  }
  ushort4 o;
  o.x = f2bf(v.x); o.y = f2bf(v.y); o.z = f2bf(v.z); o.w = f2bf(v.w);
  ((ushort4*)dst)[idx] = o;
}

// ---------------- GEMM: C = A(M,K) * B(N,K)^T, bf16 in, 128x128 tile ----------------
// MODE 0: QKV fused (N=3072). Q,K,V stored in attn fragment-major layouts (see attn_fwd).
// MODE 1: fp32 row-major store (output projection)
template<int MODE>
__global__ __launch_bounds__(256, 3) void gemm128(const ushort_t* __restrict__ A,
                                                  const ushort_t* __restrict__ Bm,
                                                  ushort_t* __restrict__ qfo,
                                                  ushort_t* __restrict__ kfo,
                                                  ushort_t* __restrict__ vfo,
                                                  float* __restrict__ ofp) {
  __shared__ ushort_t smA[128 * 64];
  __shared__ ushort_t smB[128 * 64];
  const int tid = threadIdx.x;
  const int w = tid >> 6, l = tid & 63;
  const int lg = l >> 4, ll = l & 15;
  const int lr = l >> 3, lc = (l & 7) * 8;
  const int m0 = blockIdx.y * 128, n0 = blockIdx.x * 128;
  const int wm = (w >> 1) * 64, wn = (w & 1) * 64;

  f32x4 acc[4][4];
#pragma unroll
  for (int i = 0; i < 4; ++i)
#pragma unroll
    for (int j = 0; j < 4; ++j) acc[i][j] = f32x4{0.f, 0.f, 0.f, 0.f};

  for (int k0 = 0; k0 < KDIM; k0 += 64) {
    __syncthreads();
#pragma unroll
    for (int i = 0; i < 4; ++i) {
      const int ci = w * 4 + i;
      gload16(A  + (size_t)(m0 + ci * 8 + lr) * KDIM + k0 + lc, smA + ci * 512);
      gload16(Bm + (size_t)(n0 + ci * 8 + lr) * KDIM + k0 + lc, smB + ci * 512);
    }
    __syncthreads();
#pragma unroll
    for (int ks = 0; ks < 2; ++ks) {
      bf16x8 af[4], bfr[4];
#pragma unroll
      for (int t = 0; t < 4; ++t) {
        af[t]  = *(const bf16x8*)(smA + (wm + t * 16 + ll) * 64 + ks * 32 + lg * 8);
        bfr[t] = *(const bf16x8*)(smB + (wn + t * 16 + ll) * 64 + ks * 32 + lg * 8);
      }
      __builtin_amdgcn_s_setprio(1);
#pragma unroll
      for (int i = 0; i < 4; ++i)
#pragma unroll
        for (int j = 0; j < 4; ++j)
          acc[i][j] = __builtin_amdgcn_mfma_f32_16x16x32_bf16(af[i], bfr[j], acc[i][j], 0, 0, 0);
      __builtin_amdgcn_s_setprio(0);
    }
  }

#pragma unroll
  for (int i = 0; i < 4; ++i) {
#pragma unroll
    for (int j = 0; j < 4; ++j) {
      const int gm0 = m0 + wm + i * 16 + 4 * lg;
      const int gn = n0 + wn + j * 16 + ll;
      if (MODE == 0) {
        const int which = gn >> 10, nn = gn & 1023;
        const int h = nn >> 6, d = nn & 63;
        const int b = gm0 >> 11, s0 = gm0 & 2047;
        const size_t bh = (size_t)(b * 16 + h);
        if (which == 0) {
          // Q frag-major: [bh][s>>5][ks(d>>4)][lane = (d>>3&1)*32 + (s&31)][d&7]
          const int ks = d >> 4, hiv = (d >> 3) & 1, j7 = d & 7;
#pragma unroll
          for (int r = 0; r < 4; ++r) {
            const int s = s0 + r;
            qfo[((bh * 64 + (s >> 5)) * 4 + ks) * 512 + (hiv * 32 + (s & 31)) * 8 + j7] =
                f2bf(acc[i][j][r]);
          }
        } else if (which == 1) {
          // K frag-major: [bh][kt=s>>6][h2=(s>>5)&1][ks=d>>4][lane=(d>>3&1)*32+(s&31)][d&7]
          const int ks = d >> 4, hiv = (d >> 3) & 1, j7 = d & 7;
#pragma unroll
          for (int r = 0; r < 4; ++r) {
            const int s = s0 + r;
            kfo[((bh * 32 + (s >> 6)) * 8 + ((s >> 5) & 1) * 4 + ks) * 512 +
                (hiv * 32 + (s & 31)) * 8 + j7] = f2bf(acc[i][j][r]);
          }
        } else {
          // V frag-major: [bh][kt=s>>6][dh=d>>5][m=(s>>4)&3][lane=((s>>3)&1)*32+(d&31)][s&7]
          // s0 % 4 == 0 -> 4 consecutive s stay in one 8-elem block: packed 8B store
          const size_t base = ((bh * 32 + (s0 >> 6)) * 8 + (d >> 5) * 4 + ((s0 >> 4) & 3)) * 512 +
                              (((s0 >> 3) & 1) * 32 + (d & 31)) * 8 + (s0 & 7);
          const unsigned u0 = cvtpk(acc[i][j][0], acc[i][j][1]);
          const unsigned u1 = cvtpk(acc[i][j][2], acc[i][j][3]);
          *(uint2v*)(vfo + base) = uint2v{u0, u1};
        }
      } else {
#pragma unroll
        for (int r = 0; r < 4; ++r)
          ofp[(size_t)(gm0 + r) * 1024 + gn] = acc[i][j][r];
      }
    }
  }
}

// ---------------- causal flash attention v4: LDS-free, fragment-major operands ----------------
// grid (16, 32): x = q-tile (128 rows), y = bh. 4 waves x 32 q-rows, free-running (no barriers).
// All operand loads are lane-contiguous 1KB (fragment-major global layout written by gemm<0>).
__global__ __launch_bounds__(256, 2) void attn_fwd(const ushort_t* __restrict__ Qf,
                                                   const ushort_t* __restrict__ Kf,
                                                   const ushort_t* __restrict__ Vf,
                                                   ushort_t* __restrict__ ao) {
  const int tid = threadIdx.x;
  const int w = tid >> 6, l = tid & 63;
  const int l31 = l & 31, hi = l >> 5;
  const int bh = blockIdx.y;
  // complementary pairing: batch 0 vs batch 1 get qx and 15-qx
  const int qx = ((bh >> 4) & 1) ? (15 - (int)blockIdx.x) : (int)blockIdx.x;
  const int q0 = qx * 128;
  const int q = q0 + w * 32 + l31;           // this lane's q-row

  const ushort_t* Qw = Qf + ((size_t)bh * 64 + (q0 >> 5) + w) * 4 * 512 + l * 8;
  const ushort_t* Kb = Kf + (size_t)bh * 32 * 8 * 512 + l * 8;
  const ushort_t* Vb = Vf + (size_t)bh * 32 * 8 * 512 + l * 8;

  // Q fragments: coalesced 1KB loads
  bf16x8 qf[4];
#pragma unroll
  for (int ks = 0; ks < 4; ++ks)
    qf[ks] = *(const bf16x8*)(Qw + ks * 512);

  f32x16 oT[2];
#pragma unroll
  for (int dh = 0; dh < 2; ++dh)
#pragma unroll
    for (int r = 0; r < 16; ++r) oT[dh][r] = 0.f;
  float mi = -3.0e38f, li = 0.f;

  const float SCL2 = 0.18033688011112042f;   // (1/8) * log2(e)
  const int myNkt = (q0 + 32 * w + 31) / 64 + 1;   // causal per-wave trip count

  // prefetch K fragments for tile 0
  bf16x8 kf[8];
#pragma unroll
  for (int f = 0; f < 8; ++f) kf[f] = *(const bf16x8*)(Kb + f * 512);

  for (int kt = 0; kt < myNkt; ++kt) {
    // ---- V loads for current tile (independent of QK result; issue early) ----
    const ushort_t* Vt_ = Vb + (size_t)kt * 8 * 512;
    bf16x8 vf[8];
#pragma unroll
    for (int f = 0; f < 8; ++f) vf[f] = *(const bf16x8*)(Vt_ + f * 512);

    // ---- QK^T: S^T[kv][q] ----
    f32x16 sc[2];
#pragma unroll
    for (int h2 = 0; h2 < 2; ++h2)
#pragma unroll
      for (int r = 0; r < 16; ++r) sc[h2][r] = 0.f;
    __builtin_amdgcn_s_setprio(1);
#pragma unroll
    for (int h2 = 0; h2 < 2; ++h2)
#pragma unroll
      for (int ks = 0; ks < 4; ++ks)
        sc[h2] = __builtin_amdgcn_mfma_f32_32x32x16_bf16(kf[h2 * 4 + ks], qf[ks], sc[h2], 0, 0, 0);
    __builtin_amdgcn_s_setprio(0);

    // ---- prefetch next tile's K fragments (hidden under softmax+PV) ----
    const bool more = (kt + 1 < myNkt);
    bf16x8 kfn[8];
    if (more) {
      const ushort_t* Kt_ = Kb + (size_t)(kt + 1) * 8 * 512;
#pragma unroll
      for (int f = 0; f < 8; ++f) kfn[f] = *(const bf16x8*)(Kt_ + f * 512);
    }

    // ---- causal mask (last tile of this wave only) ----
    // sc[h2][r] = S[q][kv0 + 32*h2 + crow(r,hi)], crow = (r&3)+8*(r>>2)+4*hi
    if (kt == myNkt - 1) {
      const int thr0 = q - kt * 64 - 4 * hi;
#pragma unroll
      for (int r = 0; r < 16; ++r) {
        const int cr = (r & 3) + 8 * (r >> 2);
        if (cr > thr0)      sc[0][r] = -3.0e38f;
        if (cr > thr0 - 32) sc[1][r] = -3.0e38f;
      }
    }

    // ---- in-lane row max (raw domain) + cross-half swap ----
    float t8[8];
#pragma unroll
    for (int r = 0; r < 8; ++r)
      t8[r] = fmaxf(fmaxf(sc[0][r], sc[0][r + 8]), fmaxf(sc[1][r], sc[1][r + 8]));
    float mx = fmaxf(fmaxf(fmaxf(t8[0], t8[1]), fmaxf(t8[2], t8[3])),
                     fmaxf(fmaxf(t8[4], t8[5]), fmaxf(t8[6], t8[7])));
    mx = swap_max(mx);

    // ---- defer-max rescale (T13, THR = 8 in exp2 domain = 44.36 raw) ----
    if (!__all(mx <= mi + 44.0f)) {
      const float mnew = fmaxf(mi, mx);
      const float al = __builtin_amdgcn_exp2f((mi - mnew) * SCL2);
      li *= al;
#pragma unroll
      for (int dh = 0; dh < 2; ++dh)
#pragma unroll
        for (int r = 0; r < 16; ++r) oT[dh][r] *= al;
      mi = mnew;
    }

    // ---- P = exp2(S*scale - mi*scale), in-lane sum tree ----
    const float ms = mi * SCL2;
#pragma unroll
    for (int h2 = 0; h2 < 2; ++h2)
#pragma unroll
      for (int r = 0; r < 16; ++r)
        sc[h2][r] = __builtin_amdgcn_exp2f(__builtin_fmaf(sc[h2][r], SCL2, -ms));
    float s8[8];
#pragma unroll
    for (int r = 0; r < 8; ++r)
      s8[r] = (sc[0][r] + sc[0][r + 8]) + (sc[1][r] + sc[1][r + 8]);
    float sum = ((s8[0] + s8[1]) + (s8[2] + s8[3])) + ((s8[4] + s8[5]) + (s8[6] + s8[7]));
    li += swap_sum(sum);

    // ---- pack P -> bf16 B-fragments (T12: cvt_pk + permlane32_swap builtin) ----
    bf16x8 pf[4];
#pragma unroll
    for (int m = 0; m < 4; ++m) {
      const int H = m >> 1, base = (m & 1) * 8;
      const unsigned a0 = cvtpk(sc[H][base + 0], sc[H][base + 1]);
      const unsigned a1 = cvtpk(sc[H][base + 2], sc[H][base + 3]);
      const unsigned a2 = cvtpk(sc[H][base + 4], sc[H][base + 5]);
      const unsigned a3 = cvtpk(sc[H][base + 6], sc[H][base + 7]);
      const uint2v r02 = plswap(a0, a2);   // {new a0, new a2}
      const uint2v r13 = plswap(a1, a3);
      union { unsigned u[4]; bf16x8 v; } cv;
      cv.u[0] = r02[0]; cv.u[1] = r13[0]; cv.u[2] = r02[1]; cv.u[3] = r13[1];
      pf[m] = cv.v;
    }

    // ---- PV: O^T[d][q] += V^T[d][kv] * P^T[kv][q] ----
    __builtin_amdgcn_s_setprio(1);
#pragma unroll
    for (int dh = 0; dh < 2; ++dh)
#pragma unroll
      for (int m = 0; m < 4; ++m)
        oT[dh] = __builtin_amdgcn_mfma_f32_32x32x16_bf16(vf[dh * 4 + m], pf[m], oT[dh], 0, 0, 0);
    __builtin_amdgcn_s_setprio(0);

    if (more) {
#pragma unroll
      for (int f = 0; f < 8; ++f) kf[f] = kfn[f];
    }
  }

  // ---- epilogue: O = O^T / li, packed 8B stores to (b, s, h*64+d) ----
  const float inv = 1.f / li;
  const int b = bh >> 4, h = bh & 15;
  ushort_t* orow = ao + ((size_t)b * 2048 + q) * 1024 + h * 64;
#pragma unroll
  for (int dh = 0; dh < 2; ++dh)
#pragma unroll
    for (int rg = 0; rg < 4; ++rg) {
      const unsigned u0 = cvtpk(oT[dh][4 * rg + 0] * inv, oT[dh][4 * rg + 1] * inv);
      const unsigned u1 = cvtpk(oT[dh][4 * rg + 2] * inv, oT[dh][4 * rg + 3] * inv);
      *(uint2v*)(orow + dh * 32 + hi * 4 + rg * 8) = uint2v{u0, u1};
    }
}

// ---------------- launch ----------------
extern "C" void kernel_launch(void* const* d_in, const int* in_sizes, int n_in,
                              void* d_out, int out_size, void* d_ws, size_t ws_size,
                              hipStream_t stream) {
  (void)in_sizes; (void)n_in; (void)out_size; (void)ws_size;
  const float* x  = (const float*)d_in[0];
  const float* wq = (const float*)d_in[1];
  const float* wk = (const float*)d_in[2];
  const float* wv = (const float*)d_in[3];
  const float* wo = (const float*)d_in[4];

  char* ws = (char*)d_ws;
  ushort_t* xb  = (ushort_t*)ws;                     // 8 MiB; reused as attn-out later
  ushort_t* wb  = (ushort_t*)(ws + (8u  << 20));     // 8 MiB: Wq,Wk,Wv,Wo bf16 contiguous
  ushort_t* qf  = (ushort_t*)(ws + (16u << 20));     // 8 MiB: Q fragment-major
  ushort_t* kf  = (ushort_t*)(ws + (24u << 20));     // 8 MiB: K fragment-major
  ushort_t* vf  = (ushort_t*)(ws + (40u << 20));     // 8 MiB: V fragment-major
  ushort_t* ao  = xb;                                // attention output (b,s,h*64+d)
  float* out = (float*)d_out;

  cast_all<<<8192, 256, 0, stream>>>(x, wq, wk, wv, wo, xb, wb);
  gemm128<0><<<dim3(24, 32), 256, 0, stream>>>(xb, wb, qf, kf, vf, nullptr);
  attn_fwd  <<<dim3(16, 32), 256, 0, stream>>>(qf, kf, vf, ao);
  gemm128<1><<<dim3(8, 32), 256, 0, stream>>>(ao, wb + 3 * 1048576, nullptr, nullptr, nullptr, out);
}

// Round 6
// 174.537 us; speedup vs baseline: 1.2860x; 1.0120x over previous
//
#include <hip/hip_runtime.h>
#include <hip/hip_bf16.h>

typedef __bf16 bf16x8 __attribute__((ext_vector_type(8)));
typedef float f32x4 __attribute__((ext_vector_type(4)));
typedef float f32x16 __attribute__((ext_vector_type(16)));
typedef unsigned short ushort_t;
typedef unsigned int uint2v __attribute__((ext_vector_type(2)));

#define DEVI __device__ __forceinline__

static constexpr int KDIM = 1024;   // d_model
static constexpr int SEQ  = 2048;
static constexpr size_t TEN = 4194304; // 4096*1024 elements per tensor

DEVI ushort_t f2bf(float f) {
  union { float f; unsigned u; } a; a.f = f;
  unsigned u = a.u;
  return (ushort_t)((u + 0x7FFFu + ((u >> 16) & 1u)) >> 16);
}

DEVI unsigned cvtpk(float lo, float hi) {   // word = {bf16(hi)<<16 | bf16(lo)}
  unsigned r;
  asm("v_cvt_pk_bf16_f32 %0, %1, %2" : "=v"(r) : "v"(lo), "v"(hi));
  return r;
}

// validated permlane path (m240/m214): builtin, compiler handles hazards.
DEVI uint2v plswap(unsigned a, unsigned b) {
  return __builtin_amdgcn_permlane32_swap(a, b, 0, 0);
}
DEVI float swap_max(float x) {
  union { float f; unsigned u; } a; a.f = x;
  const uint2v r = plswap(a.u, a.u);
  union { unsigned u; float f; } p0, p1; p0.u = r[0]; p1.u = r[1];
  return fmaxf(p0.f, p1.f);
}
DEVI float swap_sum(float x) {
  union { float f; unsigned u; } a; a.f = x;
  const uint2v r = plswap(a.u, a.u);
  union { unsigned u; float f; } p0, p1; p0.u = r[0]; p1.u = r[1];
  return p0.f + p1.f;
}

DEVI void gload16(const ushort_t* g, ushort_t* l) {
  __builtin_amdgcn_global_load_lds(
      (const __attribute__((address_space(1))) void*)g,
      (__attribute__((address_space(3))) void*)l,
      16, 0, 0);
}

// ---------------- fused casts: x (1M float4) then Wq|Wk|Wv|Wo (1M float4) ----------------
__global__ void cast_all(const float* __restrict__ x,
                         const float* __restrict__ w0, const float* __restrict__ w1,
                         const float* __restrict__ w2, const float* __restrict__ w3,
                         ushort_t* __restrict__ xb, ushort_t* __restrict__ wb) {
  const int i = blockIdx.x * 256 + threadIdx.x;   // [0, 2M)
  float4 v; ushort_t* dst; int idx;
  if (i < (1 << 20)) {
    v = ((const float4*)x)[i]; dst = xb; idx = i;
  } else {
    const int j = i - (1 << 20);
    const int which = j >> 18;
    const float* w = which == 0 ? w0 : which == 1 ? w1 : which == 2 ? w2 : w3;
    v = ((const float4*)w)[j & 262143]; dst = wb; idx = j;
  }
  ushort4 o;
  o.x = f2bf(v.x); o.y = f2bf(v.y); o.z = f2bf(v.z); o.w = f2bf(v.w);
  ((ushort4*)dst)[idx] = o;
}

// ---------------- QKV GEMM: 256x256 tile, 8-phase counted-vmcnt schedule ----------------
// C = A(4096,1024) * B(3072,1024)^T. 512 thr = 8 waves (2M x 4N), per-wave C = 128x64.
// LDS: [dbuf][A/B][khalf][256 rows][32 cols] = 128 KiB. Swizzle col ^= ((row>>1)&3)<<3,
// applied on the GLOBAL source (linear LDS dest, m173 pattern) and on ds_read addresses.
DEVI void stage_half(const ushort_t* __restrict__ G, int rowbase, int kcol,
                     ushort_t* lbase, int tid) {
#pragma unroll
  for (int rd = 0; rd < 2; ++rd) {
    const int row = rd * 128 + (tid >> 2), cg = tid & 3;
    const int gcol = kcol + ((cg ^ ((row >> 1) & 3)) << 3);
    gload16(G + (size_t)(rowbase + row) * 1024 + gcol, lbase + row * 32 + cg * 8);
  }
}

__global__ __launch_bounds__(512, 2) void gemm256_qkv(const ushort_t* __restrict__ A,
                                                      const ushort_t* __restrict__ Bm,
                                                      ushort_t* __restrict__ qfo,
                                                      ushort_t* __restrict__ kfo,
                                                      ushort_t* __restrict__ vfo) {
  __shared__ ushort_t sm[2][2][2][8192];
  const int tid = threadIdx.x;
  const int wid = tid >> 6, l = tid & 63;
  const int wm = wid >> 2, wn = wid & 3;
  const int lg = l >> 4, ll = l & 15;
  // bijective XCD swizzle: nwg = 192 = 8 * 24
  const int orig = blockIdx.x;
  const int wg = (orig & 7) * 24 + (orig >> 3);
  const int bx = wg % 12, by = wg / 12;
  const int m0 = by * 256, n0 = bx * 256;

  f32x4 acc[8][4];
#pragma unroll
  for (int i = 0; i < 8; ++i)
#pragma unroll
    for (int j = 0; j < 4; ++j) acc[i][j] = f32x4{0.f, 0.f, 0.f, 0.f};

#define STG(T, MAT, KH) do { if ((T) < 16) \
    stage_half((MAT) ? Bm : A, (MAT) ? n0 : m0, (T) * 64 + (KH) * 32, \
               &sm[(T) & 1][MAT][KH][0], tid); } while (0)
#define BARX do { asm volatile("" ::: "memory"); __builtin_amdgcn_s_barrier(); \
                  asm volatile("" ::: "memory"); } while (0)
#define PHASE(P, KH, MH, STG_STMT, WAIT_STMT) do {                              \
    bf16x8 af_[4], bf_[4];                                                      \
    _Pragma("unroll")                                                           \
    for (int mr = 0; mr < 4; ++mr) {                                            \
      const int ra = wm * 128 + ((MH) * 4 + mr) * 16 + ll;                      \
      af_[mr] = *(const bf16x8*)&sm[P][0][KH][ra * 32 + ((lg ^ ((ra >> 1) & 3)) << 3)]; \
    }                                                                           \
    _Pragma("unroll")                                                           \
    for (int nr = 0; nr < 4; ++nr) {                                            \
      const int rb = wn * 64 + nr * 16 + ll;                                    \
      bf_[nr] = *(const bf16x8*)&sm[P][1][KH][rb * 32 + ((lg ^ ((rb >> 1) & 3)) << 3)]; \
    }                                                                           \
    STG_STMT;                                                                   \
    BARX;                                                                       \
    __builtin_amdgcn_s_setprio(1);                                              \
    _Pragma("unroll")                                                           \
    for (int mr = 0; mr < 4; ++mr)                                              \
      _Pragma("unroll")                                                         \
      for (int nr = 0; nr < 4; ++nr)                                            \
        acc[(MH) * 4 + mr][nr] = __builtin_amdgcn_mfma_f32_16x16x32_bf16(       \
            af_[mr], bf_[nr], acc[(MH) * 4 + mr][nr], 0, 0, 0);                 \
    __builtin_amdgcn_s_setprio(0);                                              \
    WAIT_STMT;                                                                  \
    BARX;                                                                       \
  } while (0)
#define WAIT4 asm volatile("s_waitcnt vmcnt(4)" ::: "memory")
#define WAIT0 asm volatile("s_waitcnt vmcnt(0)" ::: "memory")

  // prologue: tile0 all 4 halves + tile1 k0 halves; land tile0, leave tile1-k0 in flight
  STG(0, 0, 0); STG(0, 1, 0); STG(0, 0, 1); STG(0, 1, 1); STG(1, 0, 0); STG(1, 1, 0);
  WAIT4;
  BARX;

  for (int I = 0; I < 7; ++I) {
    const int T = 2 * I;
    PHASE(0, 0, 0, STG(T + 1, 0, 1), );
    PHASE(0, 0, 1, STG(T + 1, 1, 1), );
    PHASE(0, 1, 0, STG(T + 2, 0, 0), );
    PHASE(0, 1, 1, STG(T + 2, 1, 0), WAIT4);
    PHASE(1, 0, 0, STG(T + 2, 0, 1), );
    PHASE(1, 0, 1, STG(T + 2, 1, 1), );
    PHASE(1, 1, 0, STG(T + 3, 0, 0), );
    PHASE(1, 1, 1, STG(T + 3, 1, 0), WAIT4);
  }
  // last iteration (T=14): only t15-k1 staging remains; full drain at phase 4
  PHASE(0, 0, 0, STG(15, 0, 1), );
  PHASE(0, 0, 1, STG(15, 1, 1), );
  PHASE(0, 1, 0, , );
  PHASE(0, 1, 1, , WAIT0);
  PHASE(1, 0, 0, , );
  PHASE(1, 0, 1, , );
  PHASE(1, 1, 0, , );
  PHASE(1, 1, 1, , );

#undef STG
#undef PHASE
#undef WAIT4
#undef WAIT0
#undef BARX

  // epilogue: scatter into attn fragment-major layouts (same math as round-5)
#pragma unroll
  for (int mr = 0; mr < 8; ++mr) {
#pragma unroll
    for (int nr = 0; nr < 4; ++nr) {
      const int gm0 = m0 + wm * 128 + mr * 16 + 4 * lg;
      const int gn = n0 + wn * 64 + nr * 16 + ll;
      const int which = gn >> 10, nn = gn & 1023;
      const int h = nn >> 6, d = nn & 63;
      const int b = gm0 >> 11, s0 = gm0 & 2047;
      const size_t bh = (size_t)(b * 16 + h);
      if (which == 0) {
        const int ks = d >> 4, hiv = (d >> 3) & 1, j7 = d & 7;
#pragma unroll
        for (int r = 0; r < 4; ++r) {
          const int s = s0 + r;
          qfo[((bh * 64 + (s >> 5)) * 4 + ks) * 512 + (hiv * 32 + (s & 31)) * 8 + j7] =
              f2bf(acc[mr][nr][r]);
        }
      } else if (which == 1) {
        const int ks = d >> 4, hiv = (d >> 3) & 1, j7 = d & 7;
#pragma unroll
        for (int r = 0; r < 4; ++r) {
          const int s = s0 + r;
          kfo[((bh * 32 + (s >> 6)) * 8 + ((s >> 5) & 1) * 4 + ks) * 512 +
              (hiv * 32 + (s & 31)) * 8 + j7] = f2bf(acc[mr][nr][r]);
        }
      } else {
        const size_t base = ((bh * 32 + (s0 >> 6)) * 8 + (d >> 5) * 4 + ((s0 >> 4) & 3)) * 512 +
                            (((s0 >> 3) & 1) * 32 + (d & 31)) * 8 + (s0 & 7);
        const unsigned u0 = cvtpk(acc[mr][nr][0], acc[mr][nr][1]);
        const unsigned u1 = cvtpk(acc[mr][nr][2], acc[mr][nr][3]);
        *(uint2v*)(vfo + base) = uint2v{u0, u1};
      }
    }
  }
}

// ---------------- output projection GEMM: 128x128 tile (m97 structure) ----------------
__global__ __launch_bounds__(256, 3) void gemm_out(const ushort_t* __restrict__ A,
                                                   const ushort_t* __restrict__ Bm,
                                                   float* __restrict__ ofp) {
  __shared__ ushort_t smA[128 * 64];
  __shared__ ushort_t smB[128 * 64];
  const int tid = threadIdx.x;
  const int w = tid >> 6, l = tid & 63;
  const int lg = l >> 4, ll = l & 15;
  const int lr = l >> 3, lc = (l & 7) * 8;
  const int m0 = blockIdx.y * 128, n0 = blockIdx.x * 128;
  const int wm = (w >> 1) * 64, wn = (w & 1) * 64;

  f32x4 acc[4][4];
#pragma unroll
  for (int i = 0; i < 4; ++i)
#pragma unroll
    for (int j = 0; j < 4; ++j) acc[i][j] = f32x4{0.f, 0.f, 0.f, 0.f};

  for (int k0 = 0; k0 < KDIM; k0 += 64) {
    __syncthreads();
#pragma unroll
    for (int i = 0; i < 4; ++i) {
      const int ci = w * 4 + i;
      gload16(A  + (size_t)(m0 + ci * 8 + lr) * KDIM + k0 + lc, smA + ci * 512);
      gload16(Bm + (size_t)(n0 + ci * 8 + lr) * KDIM + k0 + lc, smB + ci * 512);
    }
    __syncthreads();
#pragma unroll
    for (int ks = 0; ks < 2; ++ks) {
      bf16x8 af[4], bfr[4];
#pragma unroll
      for (int t = 0; t < 4; ++t) {
        af[t]  = *(const bf16x8*)(smA + (wm + t * 16 + ll) * 64 + ks * 32 + lg * 8);
        bfr[t] = *(const bf16x8*)(smB + (wn + t * 16 + ll) * 64 + ks * 32 + lg * 8);
      }
      __builtin_amdgcn_s_setprio(1);
#pragma unroll
      for (int i = 0; i < 4; ++i)
#pragma unroll
        for (int j = 0; j < 4; ++j)
          acc[i][j] = __builtin_amdgcn_mfma_f32_16x16x32_bf16(af[i], bfr[j], acc[i][j], 0, 0, 0);
      __builtin_amdgcn_s_setprio(0);
    }
  }

#pragma unroll
  for (int i = 0; i < 4; ++i)
#pragma unroll
    for (int j = 0; j < 4; ++j) {
      const int gm0 = m0 + wm + i * 16 + 4 * lg;
      const int gn = n0 + wn + j * 16 + ll;
#pragma unroll
      for (int r = 0; r < 4; ++r)
        ofp[(size_t)(gm0 + r) * 1024 + gn] = acc[i][j][r];
    }
}

// ---------------- causal flash attention v4: LDS-free, fragment-major operands ----------------
__global__ __launch_bounds__(256, 2) void attn_fwd(const ushort_t* __restrict__ Qf,
                                                   const ushort_t* __restrict__ Kf,
                                                   const ushort_t* __restrict__ Vf,
                                                   ushort_t* __restrict__ ao) {
  const int tid = threadIdx.x;
  const int w = tid >> 6, l = tid & 63;
  const int l31 = l & 31, hi = l >> 5;
  const int bh = blockIdx.y;
  const int qx = ((bh >> 4) & 1) ? (15 - (int)blockIdx.x) : (int)blockIdx.x;
  const int q0 = qx * 128;
  const int q = q0 + w * 32 + l31;

  const ushort_t* Qw = Qf + ((size_t)bh * 64 + (q0 >> 5) + w) * 4 * 512 + l * 8;
  const ushort_t* Kb = Kf + (size_t)bh * 32 * 8 * 512 + l * 8;
  const ushort_t* Vb = Vf + (size_t)bh * 32 * 8 * 512 + l * 8;

  bf16x8 qf[4];
#pragma unroll
  for (int ks = 0; ks < 4; ++ks)
    qf[ks] = *(const bf16x8*)(Qw + ks * 512);

  f32x16 oT[2];
#pragma unroll
  for (int dh = 0; dh < 2; ++dh)
#pragma unroll
    for (int r = 0; r < 16; ++r) oT[dh][r] = 0.f;
  float mi = -3.0e38f, li = 0.f;

  const float SCL2 = 0.18033688011112042f;   // (1/8) * log2(e)
  const int myNkt = (q0 + 32 * w + 31) / 64 + 1;

  bf16x8 kf[8];
#pragma unroll
  for (int f = 0; f < 8; ++f) kf[f] = *(const bf16x8*)(Kb + f * 512);

  for (int kt = 0; kt < myNkt; ++kt) {
    const ushort_t* Vt_ = Vb + (size_t)kt * 8 * 512;
    bf16x8 vf[8];
#pragma unroll
    for (int f = 0; f < 8; ++f) vf[f] = *(const bf16x8*)(Vt_ + f * 512);

    f32x16 sc[2];
#pragma unroll
    for (int h2 = 0; h2 < 2; ++h2)
#pragma unroll
      for (int r = 0; r < 16; ++r) sc[h2][r] = 0.f;
    __builtin_amdgcn_s_setprio(1);
#pragma unroll
    for (int h2 = 0; h2 < 2; ++h2)
#pragma unroll
      for (int ks = 0; ks < 4; ++ks)
        sc[h2] = __builtin_amdgcn_mfma_f32_32x32x16_bf16(kf[h2 * 4 + ks], qf[ks], sc[h2], 0, 0, 0);
    __builtin_amdgcn_s_setprio(0);

    const bool more = (kt + 1 < myNkt);
    bf16x8 kfn[8];
    if (more) {
      const ushort_t* Kt_ = Kb + (size_t)(kt + 1) * 8 * 512;
#pragma unroll
      for (int f = 0; f < 8; ++f) kfn[f] = *(const bf16x8*)(Kt_ + f * 512);
    }

    if (kt == myNkt - 1) {
      const int thr0 = q - kt * 64 - 4 * hi;
#pragma unroll
      for (int r = 0; r < 16; ++r) {
        const int cr = (r & 3) + 8 * (r >> 2);
        if (cr > thr0)      sc[0][r] = -3.0e38f;
        if (cr > thr0 - 32) sc[1][r] = -3.0e38f;
      }
    }

    float t8[8];
#pragma unroll
    for (int r = 0; r < 8; ++r)
      t8[r] = fmaxf(fmaxf(sc[0][r], sc[0][r + 8]), fmaxf(sc[1][r], sc[1][r + 8]));
    float mx = fmaxf(fmaxf(fmaxf(t8[0], t8[1]), fmaxf(t8[2], t8[3])),
                     fmaxf(fmaxf(t8[4], t8[5]), fmaxf(t8[6], t8[7])));
    mx = swap_max(mx);

    if (!__all(mx <= mi + 44.0f)) {
      const float mnew = fmaxf(mi, mx);
      const float al = __builtin_amdgcn_exp2f((mi - mnew) * SCL2);
      li *= al;
#pragma unroll
      for (int dh = 0; dh < 2; ++dh)
#pragma unroll
        for (int r = 0; r < 16; ++r) oT[dh][r] *= al;
      mi = mnew;
    }

    const float ms = mi * SCL2;
#pragma unroll
    for (int h2 = 0; h2 < 2; ++h2)
#pragma unroll
      for (int r = 0; r < 16; ++r)
        sc[h2][r] = __builtin_amdgcn_exp2f(__builtin_fmaf(sc[h2][r], SCL2, -ms));
    float s8[8];
#pragma unroll
    for (int r = 0; r < 8; ++r)
      s8[r] = (sc[0][r] + sc[0][r + 8]) + (sc[1][r] + sc[1][r + 8]);
    float sum = ((s8[0] + s8[1]) + (s8[2] + s8[3])) + ((s8[4] + s8[5]) + (s8[6] + s8[7]));
    li += swap_sum(sum);

    bf16x8 pf[4];
#pragma unroll
    for (int m = 0; m < 4; ++m) {
      const int H = m >> 1, base = (m & 1) * 8;
      const unsigned a0 = cvtpk(sc[H][base + 0], sc[H][base + 1]);
      const unsigned a1 = cvtpk(sc[H][base + 2], sc[H][base + 3]);
      const unsigned a2 = cvtpk(sc[H][base + 4], sc[H][base + 5]);
      const unsigned a3 = cvtpk(sc[H][base + 6], sc[H][base + 7]);
      const uint2v r02 = plswap(a0, a2);
      const uint2v r13 = plswap(a1, a3);
      union { unsigned u[4]; bf16x8 v; } cv;
      cv.u[0] = r02[0]; cv.u[1] = r13[0]; cv.u[2] = r02[1]; cv.u[3] = r13[1];
      pf[m] = cv.v;
    }

    __builtin_amdgcn_s_setprio(1);
#pragma unroll
    for (int dh = 0; dh < 2; ++dh)
#pragma unroll
      for (int m = 0; m < 4; ++m)
        oT[dh] = __builtin_amdgcn_mfma_f32_32x32x16_bf16(vf[dh * 4 + m], pf[m], oT[dh], 0, 0, 0);
    __builtin_amdgcn_s_setprio(0);

    if (more) {
#pragma unroll
      for (int f = 0; f < 8; ++f) kf[f] = kfn[f];
    }
  }

  const float inv = 1.f / li;
  const int b = bh >> 4, h = bh & 15;
  ushort_t* orow = ao + ((size_t)b * 2048 + q) * 1024 + h * 64;
#pragma unroll
  for (int dh = 0; dh < 2; ++dh)
#pragma unroll
    for (int rg = 0; rg < 4; ++rg) {
      const unsigned u0 = cvtpk(oT[dh][4 * rg + 0] * inv, oT[dh][4 * rg + 1] * inv);
      const unsigned u1 = cvtpk(oT[dh][4 * rg + 2] * inv, oT[dh][4 * rg + 3] * inv);
      *(uint2v*)(orow + dh * 32 + hi * 4 + rg * 8) = uint2v{u0, u1};
    }
}

// ---------------- launch ----------------
extern "C" void kernel_launch(void* const* d_in, const int* in_sizes, int n_in,
                              void* d_out, int out_size, void* d_ws, size_t ws_size,
                              hipStream_t stream) {
  (void)in_sizes; (void)n_in; (void)out_size; (void)ws_size;
  const float* x  = (const float*)d_in[0];
  const float* wq = (const float*)d_in[1];
  const float* wk = (const float*)d_in[2];
  const float* wv = (const float*)d_in[3];
  const float* wo = (const float*)d_in[4];

  char* ws = (char*)d_ws;
  ushort_t* xb  = (ushort_t*)ws;                     // 8 MiB; reused as attn-out later
  ushort_t* wb  = (ushort_t*)(ws + (8u  << 20));     // 8 MiB: Wq,Wk,Wv,Wo bf16 contiguous
  ushort_t* qf  = (ushort_t*)(ws + (16u << 20));     // 8 MiB: Q fragment-major
  ushort_t* kf  = (ushort_t*)(ws + (24u << 20));     // 8 MiB: K fragment-major
  ushort_t* vf  = (ushort_t*)(ws + (40u << 20));     // 8 MiB: V fragment-major
  ushort_t* ao  = xb;                                // attention output (b,s,h*64+d)
  float* out = (float*)d_out;

  cast_all   <<<8192, 256, 0, stream>>>(x, wq, wk, wv, wo, xb, wb);
  gemm256_qkv<<<192, 512, 0, stream>>>(xb, wb, qf, kf, vf);
  attn_fwd   <<<dim3(16, 32), 256, 0, stream>>>(qf, kf, vf, ao);
  gemm_out   <<<dim3(8, 32), 256, 0, stream>>>(ao, wb + 3 * 1048576, out);
}

// Round 8
// 170.441 us; speedup vs baseline: 1.3169x; 1.0240x over previous
//
#include <hip/hip_runtime.h>
#include <hip/hip_bf16.h>

typedef __bf16 bf16x8 __attribute__((ext_vector_type(8)));
typedef float f32x4 __attribute__((ext_vector_type(4)));
typedef float f32x16 __attribute__((ext_vector_type(16)));
typedef unsigned short ushort_t;
typedef unsigned int uint2v __attribute__((ext_vector_type(2)));

#define DEVI __device__ __forceinline__

static constexpr int KDIM = 1024;   // d_model
static constexpr int SEQ  = 2048;

DEVI ushort_t f2bf(float f) {
  union { float f; unsigned u; } a; a.f = f;
  unsigned u = a.u;
  return (ushort_t)((u + 0x7FFFu + ((u >> 16) & 1u)) >> 16);
}

DEVI unsigned cvtpk(float lo, float hi) {   // word = {bf16(hi)<<16 | bf16(lo)}
  unsigned r;
  asm("v_cvt_pk_bf16_f32 %0, %1, %2" : "=v"(r) : "v"(lo), "v"(hi));
  return r;
}

// validated permlane path (m240/m214): builtin, compiler handles hazards.
DEVI uint2v plswap(unsigned a, unsigned b) {
  return __builtin_amdgcn_permlane32_swap(a, b, 0, 0);
}
DEVI float swap_max(float x) {
  union { float f; unsigned u; } a; a.f = x;
  const uint2v r = plswap(a.u, a.u);
  union { unsigned u; float f; } p0, p1; p0.u = r[0]; p1.u = r[1];
  return fmaxf(p0.f, p1.f);
}
DEVI float swap_sum(float x) {
  union { float f; unsigned u; } a; a.f = x;
  const uint2v r = plswap(a.u, a.u);
  union { unsigned u; float f; } p0, p1; p0.u = r[0]; p1.u = r[1];
  return p0.f + p1.f;
}

DEVI void gload16(const ushort_t* g, ushort_t* l) {
  __builtin_amdgcn_global_load_lds(
      (const __attribute__((address_space(1))) void*)g,
      (__attribute__((address_space(3))) void*)l,
      16, 0, 0);
}

// ---------------- fused casts: x (1M float4) then Wq|Wk|Wv|Wo (1M float4) ----------------
__global__ void cast_all(const float* __restrict__ x,
                         const float* __restrict__ w0, const float* __restrict__ w1,
                         const float* __restrict__ w2, const float* __restrict__ w3,
                         ushort_t* __restrict__ xb, ushort_t* __restrict__ wb) {
  const int i = blockIdx.x * 256 + threadIdx.x;   // [0, 2M)
  float4 v; ushort_t* dst; int idx;
  if (i < (1 << 20)) {
    v = ((const float4*)x)[i]; dst = xb; idx = i;
  } else {
    const int j = i - (1 << 20);
    const int which = j >> 18;
    const float* w = which == 0 ? w0 : which == 1 ? w1 : which == 2 ? w2 : w3;
    v = ((const float4*)w)[j & 262143]; dst = wb; idx = j;
  }
  ushort4 o;
  o.x = f2bf(v.x); o.y = f2bf(v.y); o.z = f2bf(v.z); o.w = f2bf(v.w);
  ((ushort4*)dst)[idx] = o;
}

// ---------------- QKV GEMM: 256x256 tile, 8-phase counted-vmcnt schedule ----------------
// 192 blocks: wg<128 compute Q^T/K^T (A = W rows, B = x rows -> C^T has s on lanes,
// fragments store as packed 8B directly in attn layout); wg>=128 compute V (normal
// orientation, d on lanes, packed 8B V-frag stores). Same main loop for all blocks.
DEVI void stage_half(const ushort_t* __restrict__ G, int rowbase, int kcol,
                     ushort_t* lbase, int tid) {
#pragma unroll
  for (int rd = 0; rd < 2; ++rd) {
    const int row = rd * 128 + (tid >> 2), cg = tid & 3;
    const int gcol = kcol + ((cg ^ ((row >> 1) & 3)) << 3);
    gload16(G + (size_t)(rowbase + row) * 1024 + gcol, lbase + row * 32 + cg * 8);
  }
}

__global__ __launch_bounds__(512, 2) void gemm256_qkv(const ushort_t* __restrict__ xb,
                                                      const ushort_t* __restrict__ wb,
                                                      ushort_t* __restrict__ qfo,
                                                      ushort_t* __restrict__ kfo,
                                                      ushort_t* __restrict__ vfo) {
  __shared__ ushort_t sm[2][2][2][8192];
  const int tid = threadIdx.x;
  const int wid = tid >> 6, l = tid & 63;
  const int wm = wid >> 2, wn = wid & 3;
  const int lg = l >> 4, ll = l & 15;
  // bijective XCD swizzle: nwg = 192 = 8 * 24
  const int orig = blockIdx.x;
  const int wg = (orig & 7) * 24 + (orig >> 3);

  int m0, n0;
  const ushort_t *Ap, *Bp;
  bool isV;
  if (wg < 128) {          // Q^T / K^T blocks
    m0 = (wg >> 4) * 256;  // W-row: 0..1023 = Wq, 1024..2047 = Wk
    n0 = (wg & 15) * 256;  // s: 0..4095
    Ap = wb; Bp = xb; isV = false;
  } else {                 // V blocks (normal orientation)
    const int lo = wg - 128;
    m0 = (lo >> 2) * 256;  // s rows 0..4095
    n0 = (lo & 3) * 256;   // V out-col 0..1023
    Ap = xb; Bp = wb + (size_t)2048 * 1024; isV = true;
  }

  f32x4 acc[8][4];
#pragma unroll
  for (int i = 0; i < 8; ++i)
#pragma unroll
    for (int j = 0; j < 4; ++j) acc[i][j] = f32x4{0.f, 0.f, 0.f, 0.f};

#define STG(T, MAT, KH) do { if ((T) < 16) \
    stage_half((MAT) ? Bp : Ap, (MAT) ? n0 : m0, (T) * 64 + (KH) * 32, \
               &sm[(T) & 1][MAT][KH][0], tid); } while (0)
#define BARX do { asm volatile("" ::: "memory"); __builtin_amdgcn_s_barrier(); \
                  asm volatile("" ::: "memory"); } while (0)
#define PHASE(P, KH, MH, STG_STMT, WAIT_STMT) do {                              \
    bf16x8 af_[4], bf_[4];                                                      \
    _Pragma("unroll")                                                           \
    for (int mr = 0; mr < 4; ++mr) {                                            \
      const int ra = wm * 128 + ((MH) * 4 + mr) * 16 + ll;                      \
      af_[mr] = *(const bf16x8*)&sm[P][0][KH][ra * 32 + ((lg ^ ((ra >> 1) & 3)) << 3)]; \
    }                                                                           \
    _Pragma("unroll")                                                           \
    for (int nr = 0; nr < 4; ++nr) {                                            \
      const int rb = wn * 64 + nr * 16 + ll;                                    \
      bf_[nr] = *(const bf16x8*)&sm[P][1][KH][rb * 32 + ((lg ^ ((rb >> 1) & 3)) << 3)]; \
    }                                                                           \
    STG_STMT;                                                                   \
    BARX;                                                                       \
    __builtin_amdgcn_s_setprio(1);                                              \
    _Pragma("unroll")                                                           \
    for (int mr = 0; mr < 4; ++mr)                                              \
      _Pragma("unroll")                                                         \
      for (int nr = 0; nr < 4; ++nr)                                            \
        acc[(MH) * 4 + mr][nr] = __builtin_amdgcn_mfma_f32_16x16x32_bf16(       \
            af_[mr], bf_[nr], acc[(MH) * 4 + mr][nr], 0, 0, 0);                 \
    __builtin_amdgcn_s_setprio(0);                                              \
    WAIT_STMT;                                                                  \
    BARX;                                                                       \
  } while (0)
#define WAIT4 asm volatile("s_waitcnt vmcnt(4)" ::: "memory")
#define WAIT0 asm volatile("s_waitcnt vmcnt(0)" ::: "memory")

  // prologue: tile0 all 4 halves + tile1 k0 halves; land tile0, leave tile1-k0 in flight
  STG(0, 0, 0); STG(0, 1, 0); STG(0, 0, 1); STG(0, 1, 1); STG(1, 0, 0); STG(1, 1, 0);
  WAIT4;
  BARX;

  for (int I = 0; I < 7; ++I) {
    const int T = 2 * I;
    PHASE(0, 0, 0, STG(T + 1, 0, 1), );
    PHASE(0, 0, 1, STG(T + 1, 1, 1), );
    PHASE(0, 1, 0, STG(T + 2, 0, 0), );
    PHASE(0, 1, 1, STG(T + 2, 1, 0), WAIT4);
    PHASE(1, 0, 0, STG(T + 2, 0, 1), );
    PHASE(1, 0, 1, STG(T + 2, 1, 1), );
    PHASE(1, 1, 0, STG(T + 3, 0, 0), );
    PHASE(1, 1, 1, STG(T + 3, 1, 0), WAIT4);
  }
  PHASE(0, 0, 0, STG(15, 0, 1), );
  PHASE(0, 0, 1, STG(15, 1, 1), );
  PHASE(0, 1, 0, , );
  PHASE(0, 1, 1, , WAIT0);
  PHASE(1, 0, 0, , );
  PHASE(1, 0, 1, , );
  PHASE(1, 1, 0, , );
  PHASE(1, 1, 1, , );

#undef STG
#undef PHASE
#undef WAIT4
#undef WAIT0
#undef BARX

  // ---------------- epilogue ----------------
  if (!isV) {
    // C^T fragment: row = dout (= m0&1023 + wm*128 + mr*16 + 4lg + r), col = s (lanes).
    // d-bits: ks=(dout>>4)&3, hi=lg>>1, j7=4*(lg&1)+r  -> natural attn order, 8B packed.
    const int whichK = m0 >> 10;             // 0 = Q, 1 = K
    const int lgh = lg >> 1, lgb = lg & 1;
    ushort_t* const dstb = whichK ? kfo : qfo;
#pragma unroll
    for (int mr = 0; mr < 8; ++mr) {
      const int dout = (m0 & 1023) + wm * 128 + mr * 16;   // +4lg+r implicit
      const int h = dout >> 6;
      const int ks = (dout >> 4) & 3;
#pragma unroll
      for (int nr = 0; nr < 4; ++nr) {
        const int s = n0 + wn * 64 + nr * 16 + ll;
        const int b = s >> 11, s2 = s & 2047;
        const size_t bh = (size_t)(b * 16 + h);
        size_t addr;
        if (whichK == 0)
          addr = ((bh * 64 + (s2 >> 5)) * 4 + ks) * 512 + (lgh * 32 + (s2 & 31)) * 8 + lgb * 4;
        else
          addr = ((bh * 32 + (s2 >> 6)) * 8 + ((s2 >> 5) & 1) * 4 + ks) * 512 +
                 (lgh * 32 + (s2 & 31)) * 8 + lgb * 4;
        const unsigned u0 = cvtpk(acc[mr][nr][0], acc[mr][nr][1]);
        const unsigned u1 = cvtpk(acc[mr][nr][2], acc[mr][nr][3]);
        *(uint2v*)(dstb + addr) = uint2v{u0, u1};
      }
    }
  } else {
    // V frag-major: [bh][kt=s>>6][dh=d>>5][m=(s>>4)&3][lane=((s>>3)&1)*32+(d&31)][s&7]
#pragma unroll
    for (int mr = 0; mr < 8; ++mr) {
#pragma unroll
      for (int nr = 0; nr < 4; ++nr) {
        const int gm0 = m0 + wm * 128 + mr * 16 + 4 * lg;  // s
        const int gn = n0 + wn * 64 + nr * 16 + ll;        // out-col 0..1023
        const int h = gn >> 6, d = gn & 63;
        const int b = gm0 >> 11, s0 = gm0 & 2047;
        const size_t bh = (size_t)(b * 16 + h);
        const size_t base = ((bh * 32 + (s0 >> 6)) * 8 + (d >> 5) * 4 + ((s0 >> 4) & 3)) * 512 +
                            (((s0 >> 3) & 1) * 32 + (d & 31)) * 8 + (s0 & 7);
        const unsigned u0 = cvtpk(acc[mr][nr][0], acc[mr][nr][1]);
        const unsigned u1 = cvtpk(acc[mr][nr][2], acc[mr][nr][3]);
        *(uint2v*)(vfo + base) = uint2v{u0, u1};
      }
    }
  }
}

// ---------------- output projection GEMM: 128x128 tile (m97 structure) ----------------
__global__ __launch_bounds__(256, 3) void gemm_out(const ushort_t* __restrict__ A,
                                                   const ushort_t* __restrict__ Bm,
                                                   float* __restrict__ ofp) {
  __shared__ ushort_t smA[128 * 64];
  __shared__ ushort_t smB[128 * 64];
  const int tid = threadIdx.x;
  const int w = tid >> 6, l = tid & 63;
  const int lg = l >> 4, ll = l & 15;
  const int lr = l >> 3, lc = (l & 7) * 8;
  const int m0 = blockIdx.y * 128, n0 = blockIdx.x * 128;
  const int wm = (w >> 1) * 64, wn = (w & 1) * 64;

  f32x4 acc[4][4];
#pragma unroll
  for (int i = 0; i < 4; ++i)
#pragma unroll
    for (int j = 0; j < 4; ++j) acc[i][j] = f32x4{0.f, 0.f, 0.f, 0.f};

  for (int k0 = 0; k0 < KDIM; k0 += 64) {
    __syncthreads();
#pragma unroll
    for (int i = 0; i < 4; ++i) {
      const int ci = w * 4 + i;
      gload16(A  + (size_t)(m0 + ci * 8 + lr) * KDIM + k0 + lc, smA + ci * 512);
      gload16(Bm + (size_t)(n0 + ci * 8 + lr) * KDIM + k0 + lc, smB + ci * 512);
    }
    __syncthreads();
#pragma unroll
    for (int ks = 0; ks < 2; ++ks) {
      bf16x8 af[4], bfr[4];
#pragma unroll
      for (int t = 0; t < 4; ++t) {
        af[t]  = *(const bf16x8*)(smA + (wm + t * 16 + ll) * 64 + ks * 32 + lg * 8);
        bfr[t] = *(const bf16x8*)(smB + (wn + t * 16 + ll) * 64 + ks * 32 + lg * 8);
      }
      __builtin_amdgcn_s_setprio(1);
#pragma unroll
      for (int i = 0; i < 4; ++i)
#pragma unroll
        for (int j = 0; j < 4; ++j)
          acc[i][j] = __builtin_amdgcn_mfma_f32_16x16x32_bf16(af[i], bfr[j], acc[i][j], 0, 0, 0);
      __builtin_amdgcn_s_setprio(0);
    }
  }

#pragma unroll
  for (int i = 0; i < 4; ++i)
#pragma unroll
    for (int j = 0; j < 4; ++j) {
      const int gm0 = m0 + wm + i * 16 + 4 * lg;
      const int gn = n0 + wn + j * 16 + ll;
#pragma unroll
      for (int r = 0; r < 4; ++r)
        ofp[(size_t)(gm0 + r) * 1024 + gn] = acc[i][j][r];
    }
}

// ---------------- causal flash attention v4: LDS-free, fragment-major operands ----------------
__global__ __launch_bounds__(256, 2) void attn_fwd(const ushort_t* __restrict__ Qf,
                                                   const ushort_t* __restrict__ Kf,
                                                   const ushort_t* __restrict__ Vf,
                                                   ushort_t* __restrict__ ao) {
  const int tid = threadIdx.x;
  const int w = tid >> 6, l = tid & 63;
  const int l31 = l & 31, hi = l >> 5;
  const int bh = blockIdx.y;
  const int qx = ((bh >> 4) & 1) ? (15 - (int)blockIdx.x) : (int)blockIdx.x;
  const int q0 = qx * 128;
  const int q = q0 + w * 32 + l31;

  const ushort_t* Qw = Qf + ((size_t)bh * 64 + (q0 >> 5) + w) * 4 * 512 + l * 8;
  const ushort_t* Kb = Kf + (size_t)bh * 32 * 8 * 512 + l * 8;
  const ushort_t* Vb = Vf + (size_t)bh * 32 * 8 * 512 + l * 8;

  bf16x8 qf[4];
#pragma unroll
  for (int ks = 0; ks < 4; ++ks)
    qf[ks] = *(const bf16x8*)(Qw + ks * 512);

  f32x16 oT[2];
#pragma unroll
  for (int dh = 0; dh < 2; ++dh)
#pragma unroll
    for (int r = 0; r < 16; ++r) oT[dh][r] = 0.f;
  float mi = -3.0e38f, li = 0.f;

  const float SCL2 = 0.18033688011112042f;   // (1/8) * log2(e)
  const int myNkt = (q0 + 32 * w + 31) / 64 + 1;

  bf16x8 kf[8];
#pragma unroll
  for (int f = 0; f < 8; ++f) kf[f] = *(const bf16x8*)(Kb + f * 512);

  for (int kt = 0; kt < myNkt; ++kt) {
    const ushort_t* Vt_ = Vb + (size_t)kt * 8 * 512;
    bf16x8 vf[8];
#pragma unroll
    for (int f = 0; f < 8; ++f) vf[f] = *(const bf16x8*)(Vt_ + f * 512);

    f32x16 sc[2];
#pragma unroll
    for (int h2 = 0; h2 < 2; ++h2)
#pragma unroll
      for (int r = 0; r < 16; ++r) sc[h2][r] = 0.f;
    __builtin_amdgcn_s_setprio(1);
#pragma unroll
    for (int h2 = 0; h2 < 2; ++h2)
#pragma unroll
      for (int ks = 0; ks < 4; ++ks)
        sc[h2] = __builtin_amdgcn_mfma_f32_32x32x16_bf16(kf[h2 * 4 + ks], qf[ks], sc[h2], 0, 0, 0);
    __builtin_amdgcn_s_setprio(0);

    const bool more = (kt + 1 < myNkt);
    bf16x8 kfn[8];
    if (more) {
      const ushort_t* Kt_ = Kb + (size_t)(kt + 1) * 8 * 512;
#pragma unroll
      for (int f = 0; f < 8; ++f) kfn[f] = *(const bf16x8*)(Kt_ + f * 512);
    }

    if (kt == myNkt - 1) {
      const int thr0 = q - kt * 64 - 4 * hi;
#pragma unroll
      for (int r = 0; r < 16; ++r) {
        const int cr = (r & 3) + 8 * (r >> 2);
        if (cr > thr0)      sc[0][r] = -3.0e38f;
        if (cr > thr0 - 32) sc[1][r] = -3.0e38f;
      }
    }

    float t8[8];
#pragma unroll
    for (int r = 0; r < 8; ++r)
      t8[r] = fmaxf(fmaxf(sc[0][r], sc[0][r + 8]), fmaxf(sc[1][r], sc[1][r + 8]));
    float mx = fmaxf(fmaxf(fmaxf(t8[0], t8[1]), fmaxf(t8[2], t8[3])),
                     fmaxf(fmaxf(t8[4], t8[5]), fmaxf(t8[6], t8[7])));
    mx = swap_max(mx);

    if (!__all(mx <= mi + 44.0f)) {
      const float mnew = fmaxf(mi, mx);
      const float al = __builtin_amdgcn_exp2f((mi - mnew) * SCL2);
      li *= al;
#pragma unroll
      for (int dh = 0; dh < 2; ++dh)
#pragma unroll
        for (int r = 0; r < 16; ++r) oT[dh][r] *= al;
      mi = mnew;
    }

    const float ms = mi * SCL2;
#pragma unroll
    for (int h2 = 0; h2 < 2; ++h2)
#pragma unroll
      for (int r = 0; r < 16; ++r)
        sc[h2][r] = __builtin_amdgcn_exp2f(__builtin_fmaf(sc[h2][r], SCL2, -ms));
    float s8[8];
#pragma unroll
    for (int r = 0; r < 8; ++r)
      s8[r] = (sc[0][r] + sc[0][r + 8]) + (sc[1][r] + sc[1][r + 8]);
    float sum = ((s8[0] + s8[1]) + (s8[2] + s8[3])) + ((s8[4] + s8[5]) + (s8[6] + s8[7]));
    li += swap_sum(sum);

    bf16x8 pf[4];
#pragma unroll
    for (int m = 0; m < 4; ++m) {
      const int H = m >> 1, base = (m & 1) * 8;
      const unsigned a0 = cvtpk(sc[H][base + 0], sc[H][base + 1]);
      const unsigned a1 = cvtpk(sc[H][base + 2], sc[H][base + 3]);
      const unsigned a2 = cvtpk(sc[H][base + 4], sc[H][base + 5]);
      const unsigned a3 = cvtpk(sc[H][base + 6], sc[H][base + 7]);
      const uint2v r02 = plswap(a0, a2);
      const uint2v r13 = plswap(a1, a3);
      union { unsigned u[4]; bf16x8 v; } cv;
      cv.u[0] = r02[0]; cv.u[1] = r13[0]; cv.u[2] = r02[1]; cv.u[3] = r13[1];
      pf[m] = cv.v;
    }

    __builtin_amdgcn_s_setprio(1);
#pragma unroll
    for (int dh = 0; dh < 2; ++dh)
#pragma unroll
      for (int m = 0; m < 4; ++m)
        oT[dh] = __builtin_amdgcn_mfma_f32_32x32x16_bf16(vf[dh * 4 + m], pf[m], oT[dh], 0, 0, 0);
    __builtin_amdgcn_s_setprio(0);

    if (more) {
#pragma unroll
      for (int f = 0; f < 8; ++f) kf[f] = kfn[f];
    }
  }

  const float inv = 1.f / li;
  const int b = bh >> 4, h = bh & 15;
  ushort_t* orow = ao + ((size_t)b * 2048 + q) * 1024 + h * 64;
#pragma unroll
  for (int dh = 0; dh < 2; ++dh)
#pragma unroll
    for (int rg = 0; rg < 4; ++rg) {
      const unsigned u0 = cvtpk(oT[dh][4 * rg + 0] * inv, oT[dh][4 * rg + 1] * inv);
      const unsigned u1 = cvtpk(oT[dh][4 * rg + 2] * inv, oT[dh][4 * rg + 3] * inv);
      *(uint2v*)(orow + dh * 32 + hi * 4 + rg * 8) = uint2v{u0, u1};
    }
}

// ---------------- launch ----------------
extern "C" void kernel_launch(void* const* d_in, const int* in_sizes, int n_in,
                              void* d_out, int out_size, void* d_ws, size_t ws_size,
                              hipStream_t stream) {
  (void)in_sizes; (void)n_in; (void)out_size; (void)ws_size;
  const float* x  = (const float*)d_in[0];
  const float* wq = (const float*)d_in[1];
  const float* wk = (const float*)d_in[2];
  const float* wv = (const float*)d_in[3];
  const float* wo = (const float*)d_in[4];

  char* ws = (char*)d_ws;
  ushort_t* xb  = (ushort_t*)ws;                     // 8 MiB; reused as attn-out later
  ushort_t* wb  = (ushort_t*)(ws + (8u  << 20));     // 8 MiB: Wq,Wk,Wv,Wo bf16 contiguous
  ushort_t* qf  = (ushort_t*)(ws + (16u << 20));     // 8 MiB: Q fragment-major
  ushort_t* kf  = (ushort_t*)(ws + (24u << 20));     // 8 MiB: K fragment-major
  ushort_t* vf  = (ushort_t*)(ws + (40u << 20));     // 8 MiB: V fragment-major
  ushort_t* ao  = xb;                                // attention output (b,s,h*64+d)
  float* out = (float*)d_out;

  cast_all   <<<8192, 256, 0, stream>>>(x, wq, wk, wv, wo, xb, wb);
  gemm256_qkv<<<192, 512, 0, stream>>>(xb, wb, qf, kf, vf);
  attn_fwd   <<<dim3(16, 32), 256, 0, stream>>>(qf, kf, vf, ao);
  gemm_out   <<<dim3(8, 32), 256, 0, stream>>>(ao, wb + 3 * 1048576, out);
}